// Round 1
// baseline (1065.834 us; speedup 1.0000x reference)
//
#include <hip/hip_runtime.h>
#include <hip/hip_bf16.h>
#include <stdint.h>

#define N_TOK 8192
#define DIN   1024
#define DHID  4096
#define DOUT  1024
#define NE    8

typedef __attribute__((ext_vector_type(8))) __bf16 bf16x8;
typedef __attribute__((ext_vector_type(4))) float  f32x4;
typedef __attribute__((ext_vector_type(8))) unsigned short u16x8;

// RNE float->bf16 (finite inputs)
__device__ __forceinline__ unsigned short f2bfu(float f) {
    union { float f; unsigned u; } a; a.f = f;
    unsigned r = a.u + 0x7FFF + ((a.u >> 16) & 1);
    return (unsigned short)(r >> 16);
}

__device__ __forceinline__ void gload_lds16(const void* g, void* l) {
    __builtin_amdgcn_global_load_lds(
        (__attribute__((address_space(1))) void*)(void*)g,
        (__attribute__((address_space(3))) void*)l,
        16, 0, 0);
}

// Raw barrier + counted waits: the K-loop must NOT use __syncthreads() (it drains
// vmcnt(0) and kills the in-flight prefetch pipeline — the old structure's ceiling).
#define SBAR()   asm volatile("s_barrier" ::: "memory")
#define LGKM0()  do { asm volatile("s_waitcnt lgkmcnt(0)" ::: "memory"); \
                      __builtin_amdgcn_sched_barrier(0); } while (0)
#define VMCNT4() asm volatile("s_waitcnt vmcnt(4)" ::: "memory")
#define VMCNT0() asm volatile("s_waitcnt vmcnt(0)" ::: "memory")

// ------------- cast + transpose weights: in [R][C] f32 -> out [C][R] bf16, per expert -------------
__global__ void transpose_cast_kernel(const float* __restrict__ in, unsigned short* __restrict__ out,
                                      int R, int C) {
    __shared__ float t[64][65];
    const size_t RC = (size_t)R * C;
    const float* ine = in + (size_t)blockIdx.z * RC;
    unsigned short* oute = out + (size_t)blockIdx.z * RC;
    int c0 = blockIdx.x * 64, r0 = blockIdx.y * 64;
    int tid = threadIdx.x;
    #pragma unroll
    for (int it = 0; it < 4; it++) {
        int idx = it * 256 + tid;
        int r = idx >> 4, cq = (idx & 15) * 4;
        float4 v = *(const float4*)(ine + (size_t)(r0 + r) * C + c0 + cq);
        t[r][cq] = v.x; t[r][cq + 1] = v.y; t[r][cq + 2] = v.z; t[r][cq + 3] = v.w;
    }
    __syncthreads();
    #pragma unroll
    for (int it = 0; it < 2; it++) {
        int u = it * 256 + tid;
        int c = u >> 3, g = (u & 7) * 8;
        u16x8 o;
        #pragma unroll
        for (int v = 0; v < 8; v++) o[v] = f2bfu(t[g + v][c]);
        *(u16x8*)(oute + (size_t)(c0 + c) * R + r0 + g) = o;
    }
}

// ---------------- gating: scores, softmax, top-2, expert lists; also emits xb (x cast to bf16) ----------------
__global__ void gate_kernel(const float* __restrict__ x, const float* __restrict__ Wg,
                            const float* __restrict__ bg, int* __restrict__ counts,
                            int* __restrict__ tok_list, int* __restrict__ slot_list,
                            float* __restrict__ wslot, unsigned short* __restrict__ xb) {
    int wv = threadIdx.x >> 6, lane = threadIdx.x & 63;
    int n = blockIdx.x * 4 + wv;
    float acc[NE];
    #pragma unroll
    for (int e = 0; e < NE; e++) acc[e] = 0.f;
    const float* xr = x + (size_t)n * DIN;
    unsigned short* xbr = xb + (size_t)n * DIN;
    #pragma unroll
    for (int i = 0; i < DIN / 256; i++) {
        int d = i * 256 + lane * 4;
        float4 xv = *(const float4*)(xr + d);
        ushort4 o;
        o.x = f2bfu(xv.x); o.y = f2bfu(xv.y); o.z = f2bfu(xv.z); o.w = f2bfu(xv.w);
        *(ushort4*)(xbr + d) = o;
        const float* w = Wg + (size_t)d * NE;
        #pragma unroll
        for (int u = 0; u < 4; u++) {
            float xs = (&xv.x)[u];
            float4 w0 = *(const float4*)(w + u * NE);
            float4 w1 = *(const float4*)(w + u * NE + 4);
            acc[0] += xs * w0.x; acc[1] += xs * w0.y; acc[2] += xs * w0.z; acc[3] += xs * w0.w;
            acc[4] += xs * w1.x; acc[5] += xs * w1.y; acc[6] += xs * w1.z; acc[7] += xs * w1.w;
        }
    }
    #pragma unroll
    for (int off = 32; off; off >>= 1)
        #pragma unroll
        for (int e = 0; e < NE; e++) acc[e] += __shfl_down(acc[e], off);
    if (lane == 0) {
        float s[NE], p[NE];
        float mx = -1e30f;
        #pragma unroll
        for (int e = 0; e < NE; e++) { s[e] = acc[e] + bg[e]; mx = fmaxf(mx, s[e]); }
        float sum = 0.f;
        #pragma unroll
        for (int e = 0; e < NE; e++) { p[e] = expf(s[e] - mx); sum += p[e]; }
        float inv = 1.f / sum;
        int e0 = 0;
        #pragma unroll
        for (int e = 1; e < NE; e++) if (s[e] > s[e0]) e0 = e;
        int e1 = (e0 == 0) ? 1 : 0;
        #pragma unroll
        for (int e = 0; e < NE; e++) if (e != e0 && s[e] > s[e1]) e1 = e;
        float p0 = p[e0] * inv, p1 = p[e1] * inv;
        float rn = 1.f / (p0 + p1 + 1e-8f);
        int pos0 = atomicAdd(&counts[e0], 1);
        tok_list[e0 * N_TOK + pos0] = n; slot_list[e0 * N_TOK + pos0] = 2 * n;     wslot[e0 * N_TOK + pos0] = p0 * rn;
        int pos1 = atomicAdd(&counts[e1], 1);
        tok_list[e1 * N_TOK + pos1] = n; slot_list[e1 * N_TOK + pos1] = 2 * n + 1; wslot[e1 * N_TOK + pos1] = p1 * rn;
    }
}

// ---------------- helpers for the 8-phase GEMM ----------------
__device__ __forceinline__ void rd4(bf16x8 (&dst)[4][2], const unsigned short* base,
                                    const int (&row0)[4], const int (&ko)[2]) {
    #pragma unroll
    for (int f = 0; f < 4; f++)
        #pragma unroll
        for (int ks = 0; ks < 2; ks++)
            dst[f][ks] = *(const bf16x8*)(base + row0[f] + ko[ks]);
}
__device__ __forceinline__ void rd2(bf16x8 (&dst)[2][2], const unsigned short* base,
                                    const int (&row0)[2], const int (&ko)[2]) {
    #pragma unroll
    for (int f = 0; f < 2; f++)
        #pragma unroll
        for (int ks = 0; ks < 2; ks++)
            dst[f][ks] = *(const bf16x8*)(base + row0[f] + ko[ks]);
}
template <int MH, int NH>
__device__ __forceinline__ void mfq(f32x4 (&acc)[2][4][2][2], const bf16x8 (&av)[4][2],
                                    const bf16x8 (&bv)[2][2]) {
    #pragma unroll
    for (int mf = 0; mf < 4; mf++)
        #pragma unroll
        for (int nf = 0; nf < 2; nf++)
            #pragma unroll
            for (int ks = 0; ks < 2; ks++)
                acc[MH][mf][NH][nf] = __builtin_amdgcn_mfma_f32_16x16x32_bf16(
                    av[mf][ks], bv[nf][ks], acc[MH][mf][NH][nf], 0, 0, 0);
}

// ---------------- persistent grouped gather-GEMM, 256x256 tile, BK=64, 8-phase schedule ----------------
// m201-style schedule in plain HIP: 8 waves (2Mx4N), per-wave C = 128x64. Per K-tile, 4 phases,
// each = global 128x128 quadrant (order M0N0, M1N0, M1N1, M0N1). LDS = 2 dbuf x (A 32KB + B 32KB)
// = 128KB (dynamic). Per phase: ds_read frags + issue ONE half-tile global_load_lds prefetch ->
// s_barrier -> lgkmcnt(0)+sched_barrier -> setprio(1) -> 16 MFMA -> setprio(0) -> s_barrier.
// Counted vmcnt(4) ONCE per K-tile (never 0 in steady state): half-tile staging slots are
//   ph1: (t+1):A0   ph2: (t+1):B1    [other buffer, free]
//   ph3: (t+2):B0   ph4: (t+2):A1    [same buffer; those regions are dead after ph2/ph3]
// so at ph4, waiting to <=4 outstanding loads guarantees tile t+1 fully resident while keeping
// t+2's first 2 half-tiles in flight across the barrier.
// LDS swizzle: slot ^= row&7 on both stage-source and read (same proven scheme; 0 conflicts).
template <int KDIM, int NDIM, bool IS_GEMM1, int SPLITK>
__global__ __launch_bounds__(512, 2)
void moe_gemm(const unsigned short* __restrict__ Asrc, const unsigned short* __restrict__ Bt,
              const float* __restrict__ bias, unsigned short* __restrict__ Hdst,
              float* __restrict__ Odst, const int* __restrict__ counts,
              const int* __restrict__ tok_list, const int* __restrict__ slot_list,
              const float* __restrict__ wslot) {
    constexpr int NT_N = NDIM / 256;
    constexpr int KLEN = KDIM / SPLITK;
    constexpr int NKT  = KLEN / 64;
    static_assert((NKT & 1) == 0 && NKT >= 4, "pipeline needs even NKT >= 4");

    extern __shared__ char smem[];
    unsigned short* As = (unsigned short*)smem;            // [2][128+128 rows][64] = 64KB
    unsigned short* Bs = (unsigned short*)(smem + 65536);  // 64KB
    int*   rowid_s = (int*)(smem + 131072);
    int*   outid_s = (int*)(smem + 132096);
    float* w_s     = (float*)(smem + 133120);

    const int e = blockIdx.x & 7;        // expert pinned to XCD (round-robin block->XCD)
    const int local = blockIdx.x >> 3;   // 0..31
    const int count = counts[e];
    const int Mt = (count + 255) >> 8;
    const int items = NT_N * SPLITK * Mt;

    const int tid = threadIdx.x;
    const int lane = tid & 63;
    const int wv = tid >> 6;                 // 0..7
    const int wm2 = (wv >> 2) * 64;          // wave M offset within 128-quadrant
    const int wn2 = (wv & 3) * 32;           // wave N offset within 128-quadrant
    const int r16 = lane & 15, quad = lane >> 4;
    const int lr = lane >> 3, ls = lane & 7; // staging row-sub / slot
    const int ksrc8 = (ls ^ lr) * 8;         // swizzled source k-offset (elements)

    int arow0[4], brow0[2], koff[2];
    #pragma unroll
    for (int mf = 0; mf < 4; mf++) arow0[mf] = (wm2 + mf * 16 + r16) * 64;
    #pragma unroll
    for (int nf = 0; nf < 2; nf++) brow0[nf] = (wn2 + nf * 16 + r16) * 64;
    #pragma unroll
    for (int ks = 0; ks < 2; ks++) koff[ks] = ((ks * 4 + quad) ^ (r16 & 7)) * 8;

    const char* Abase = (const char*)Asrc;
    const char* Bbase = (const char*)(Bt + (size_t)e * NDIM * KDIM);

    for (int w_it = local; w_it < items; w_it += 32) {
        int tile_m = w_it % Mt;              // m fastest: block keeps tile_m -> A stays in L2
        int rdec = w_it / Mt;
        int tile_n = rdec % NT_N;
        int kh = rdec / NT_N;
        const int k0 = kh * KLEN;

        __syncthreads();                     // prior item's epilogue reads of outid_s/w_s done
        if (tid < 256) {
            int rr = tile_m * 256 + tid;
            if (rr >= count) rr = tile_m * 256;
            int base = e * N_TOK + rr;
            if (IS_GEMM1) { rowid_s[tid] = tok_list[base]; outid_s[tid] = slot_list[base]; }
            else          { rowid_s[tid] = slot_list[base]; outid_s[tid] = tok_list[base]; w_s[tid] = wslot[base]; }
        }
        __syncthreads();

        // per-lane 32-bit source byte offsets (k advances by t*128 bytes per K-tile)
        uint32_t aoff[2][2], boff[2][2];
        #pragma unroll
        for (int h = 0; h < 2; h++)
            #pragma unroll
            for (int g = 0; g < 2; g++) {
                int rla = h * 128 + (wv * 2 + g) * 8 + lr;
                aoff[h][g] = (uint32_t)rowid_s[rla] * (uint32_t)(KDIM * 2) + (uint32_t)(k0 + ksrc8) * 2u;
                boff[h][g] = (uint32_t)(tile_n * 256 + rla) * (uint32_t)(KDIM * 2) + (uint32_t)(k0 + ksrc8) * 2u;
            }

#define STAGE_A(t2, h) do {                                                        \
        unsigned short* _d = As + (((t2) & 1) * 16384) + (h) * 8192 + wv * 1024;   \
        gload_lds16(Abase + aoff[h][0] + (size_t)(t2) * 128, (void*)_d);           \
        gload_lds16(Abase + aoff[h][1] + (size_t)(t2) * 128, (void*)(_d + 512));   \
    } while (0)
#define STAGE_B(t2, h) do {                                                        \
        unsigned short* _d = Bs + (((t2) & 1) * 16384) + (h) * 8192 + wv * 1024;   \
        gload_lds16(Bbase + boff[h][0] + (size_t)(t2) * 128, (void*)_d);           \
        gload_lds16(Bbase + boff[h][1] + (size_t)(t2) * 128, (void*)(_d + 512));   \
    } while (0)
#define RDA(buf, Mh) rd4(av, As + (buf) * 16384 + (Mh) * 8192, arow0, koff)
#define RDB(buf, Nh) rd2(bv, Bs + (buf) * 16384 + (Nh) * 8192, brow0, koff)

        f32x4 acc[2][4][2][2];
        #pragma unroll
        for (int a0 = 0; a0 < 2; a0++)
            #pragma unroll
            for (int a1 = 0; a1 < 4; a1++)
                #pragma unroll
                for (int a2 = 0; a2 < 2; a2++)
                    #pragma unroll
                    for (int a3 = 0; a3 < 2; a3++)
                        acc[a0][a1][a2][a3] = (f32x4){0.f, 0.f, 0.f, 0.f};

        bf16x8 av[4][2], bv[2][2];

        // prologue: tile0 fully + tile1's {B0, A1} (the ph3/ph4 slots of the virtual tile -1)
        STAGE_A(0, 0); STAGE_A(0, 1); STAGE_B(0, 0); STAGE_B(0, 1);
        STAGE_B(1, 0); STAGE_A(1, 1);
        VMCNT4();            // tile0 landed; tile1's 2 halves stay in flight
        SBAR();

#define TILE_BODY(t, buf) do {                                                     \
        /* ph1: quadrant (M0,N0) */                                                \
        RDA(buf, 0); RDB(buf, 0);                                                  \
        if ((t) + 1 < NKT) STAGE_A((t) + 1, 0);                                    \
        SBAR(); LGKM0();                                                           \
        __builtin_amdgcn_s_setprio(1); mfq<0, 0>(acc, av, bv);                     \
        __builtin_amdgcn_s_setprio(0);                                             \
        SBAR();                                                                    \
        /* ph2: (M1,N0) — reuse bv */                                              \
        RDA(buf, 1);                                                               \
        if ((t) + 1 < NKT) STAGE_B((t) + 1, 1);                                    \
        SBAR(); LGKM0();                                                           \
        __builtin_amdgcn_s_setprio(1); mfq<1, 0>(acc, av, bv);                     \
        __builtin_amdgcn_s_setprio(0);                                             \
        SBAR();                                                                    \
        /* ph3: (M1,N1) — reuse av; B0 region of this buf is now dead */           \
        RDB(buf, 1);                                                               \
        if ((t) + 2 < NKT) STAGE_B((t) + 2, 0);                                    \
        SBAR(); LGKM0();                                                           \
        __builtin_amdgcn_s_setprio(1); mfq<1, 1>(acc, av, bv);                     \
        __builtin_amdgcn_s_setprio(0);                                             \
        SBAR();                                                                    \
        /* ph4: (M0,N1) — reuse bv; A1 region dead */                              \
        RDA(buf, 0);                                                               \
        if ((t) + 2 < NKT) STAGE_A((t) + 2, 1);                                    \
        SBAR(); LGKM0();                                                           \
        __builtin_amdgcn_s_setprio(1); mfq<0, 1>(acc, av, bv);                     \
        __builtin_amdgcn_s_setprio(0);                                             \
        if ((t) + 2 < NKT) { VMCNT4(); } else { VMCNT0(); }                        \
        SBAR();                                                                    \
    } while (0)

        #pragma unroll 1
        for (int tt = 0; tt < NKT; tt += 2) {
            TILE_BODY(tt, 0);
            TILE_BODY(tt + 1, 1);
        }
#undef TILE_BODY
#undef STAGE_A
#undef STAGE_B
#undef RDA
#undef RDB

        // epilogue: D row = quad*4+reg, col = r16 within each 16x16 tile
        float bias_r[2][2];
        #pragma unroll
        for (int Nh = 0; Nh < 2; Nh++)
            #pragma unroll
            for (int nf = 0; nf < 2; nf++)
                bias_r[Nh][nf] = bias[(size_t)e * NDIM + tile_n * 256 + Nh * 128 + wn2 + nf * 16 + r16];

        #pragma unroll
        for (int Mh = 0; Mh < 2; Mh++)
            #pragma unroll
            for (int mf = 0; mf < 4; mf++)
                #pragma unroll
                for (int reg = 0; reg < 4; reg++) {
                    int rr = Mh * 128 + wm2 + mf * 16 + quad * 4 + reg;
                    if (tile_m * 256 + rr >= count) continue;
                    int orow = outid_s[rr];
                    float wr = IS_GEMM1 ? 0.f : w_s[rr];
                    #pragma unroll
                    for (int Nh = 0; Nh < 2; Nh++)
                        #pragma unroll
                        for (int nf = 0; nf < 2; nf++) {
                            int col = tile_n * 256 + Nh * 128 + wn2 + nf * 16 + r16;
                            float v = acc[Mh][mf][Nh][nf][reg];
                            if (IS_GEMM1) {
                                v = fmaxf(v + bias_r[Nh][nf], 0.f);
                                Hdst[(size_t)orow * NDIM + col] = f2bfu(v);
                            } else {
                                if (kh == 0) v += bias_r[Nh][nf];
                                atomicAdd(&Odst[(size_t)orow * NDIM + col], wr * v);
                            }
                        }
                }
    }
}

extern "C" void kernel_launch(void* const* d_in, const int* in_sizes, int n_in,
                              void* d_out, int out_size, void* d_ws, size_t ws_size,
                              hipStream_t stream) {
    const float* x  = (const float*)d_in[0];
    const float* W1 = (const float*)d_in[1];
    const float* b1 = (const float*)d_in[2];
    const float* W2 = (const float*)d_in[3];
    const float* b2 = (const float*)d_in[4];
    const float* Wg = (const float*)d_in[5];
    const float* bg = (const float*)d_in[6];
    float* out = (float*)d_out;

    char* ws = (char*)d_ws;
    unsigned short* xb  = (unsigned short*)(ws + 0);            // 16 MB
    unsigned short* w1t = (unsigned short*)(ws + 16777216);     // 64 MB  [E][DHID][DIN]
    unsigned short* w2t = (unsigned short*)(ws + 83886080);     // 64 MB  [E][DOUT][DHID]
    unsigned short* h   = (unsigned short*)(ws + 150994944);    // 128 MB [2N][DHID]
    int*   counts    = (int*)(ws + 285212672);
    int*   tok_list  = (int*)(ws + 285212928);
    int*   slot_list = (int*)(ws + 285475072);
    float* wslot     = (float*)(ws + 285737216);

    constexpr int SMEM_BYTES = 134144;  // 128KB tiles + 3KB index lists
    static bool s_init = []() {
        hipFuncSetAttribute(reinterpret_cast<const void*>(&moe_gemm<DIN, DHID, true, 1>),
                            hipFuncAttributeMaxDynamicSharedMemorySize, SMEM_BYTES);
        hipFuncSetAttribute(reinterpret_cast<const void*>(&moe_gemm<DHID, DOUT, false, 4>),
                            hipFuncAttributeMaxDynamicSharedMemorySize, SMEM_BYTES);
        return true;
    }();
    (void)s_init;

    hipMemsetAsync(counts, 0, 256, stream);
    hipMemsetAsync(d_out, 0, (size_t)out_size * sizeof(float), stream);

    transpose_cast_kernel<<<dim3(DHID / 64, DIN / 64, NE), 256, 0, stream>>>(W1, w1t, DIN, DHID);
    transpose_cast_kernel<<<dim3(DOUT / 64, DHID / 64, NE), 256, 0, stream>>>(W2, w2t, DHID, DOUT);
    gate_kernel<<<N_TOK / 4, 256, 0, stream>>>(x, Wg, bg, counts, tok_list, slot_list, wslot, xb);

    moe_gemm<DIN, DHID, true, 1><<<256, 512, SMEM_BYTES, stream>>>(
        xb, w1t, b1, h, nullptr, counts, tok_list, slot_list, wslot);
    moe_gemm<DHID, DOUT, false, 4><<<256, 512, SMEM_BYTES, stream>>>(
        h, w2t, b2, nullptr, out, counts, tok_list, slot_list, wslot);
}

// Round 2
// 843.940 us; speedup vs baseline: 1.2629x; 1.2629x over previous
//
#include <hip/hip_runtime.h>
#include <hip/hip_bf16.h>
#include <stdint.h>

#define N_TOK 8192
#define DIN   1024
#define DHID  4096
#define DOUT  1024
#define NE    8

typedef __attribute__((ext_vector_type(8))) __bf16 bf16x8;
typedef __attribute__((ext_vector_type(4))) float  f32x4;
typedef __attribute__((ext_vector_type(8))) unsigned short u16x8;

// RNE float->bf16 (finite inputs)
__device__ __forceinline__ unsigned short f2bfu(float f) {
    union { float f; unsigned u; } a; a.f = f;
    unsigned r = a.u + 0x7FFF + ((a.u >> 16) & 1);
    return (unsigned short)(r >> 16);
}

__device__ __forceinline__ void gload_lds16(const void* g, void* l) {
    __builtin_amdgcn_global_load_lds(
        (__attribute__((address_space(1))) void*)(void*)g,
        (__attribute__((address_space(3))) void*)l,
        16, 0, 0);
}

// ---- 64x64 cast+transpose tile as a device function (256-thread blocks) ----
// in [R][C] f32 (expert bz) -> out [C][R] bf16. t = 64x65 f32 LDS staging.
__device__ __forceinline__ void transpose_tile(const float* __restrict__ in,
                                               unsigned short* __restrict__ out,
                                               int R, int C, int bx, int by, int bz,
                                               float (*t)[65]) {
    const size_t RC = (size_t)R * C;
    const float* ine = in + (size_t)bz * RC;
    unsigned short* oute = out + (size_t)bz * RC;
    int c0 = bx * 64, r0 = by * 64;
    int tid = threadIdx.x;
    __syncthreads();   // LDS region free (prev tile's reads / prev phase done)
    #pragma unroll
    for (int it = 0; it < 4; it++) {
        int idx = it * 256 + tid;
        int r = idx >> 4, cq = (idx & 15) * 4;
        float4 v = *(const float4*)(ine + (size_t)(r0 + r) * C + c0 + cq);
        t[r][cq] = v.x; t[r][cq + 1] = v.y; t[r][cq + 2] = v.z; t[r][cq + 3] = v.w;
    }
    __syncthreads();
    #pragma unroll
    for (int it = 0; it < 2; it++) {
        int u = it * 256 + tid;
        int c = u >> 3, g = (u & 7) * 8;
        u16x8 o;
        #pragma unroll
        for (int v = 0; v < 8; v++) o[v] = f2bfu(t[g + v][c]);
        *(u16x8*)(oute + (size_t)(c0 + c) * R + r0 + g) = o;
    }
}

// ---------------- gating + fused W1 transpose ----------------
// Gating: scores, softmax, top-2, expert lists; emits xb (x cast to bf16).
// Then each block transposes 4 tiles of W1 (8192 tiles / 2048 blocks) — w1t is
// consumed by GEMM1 (next launch), same dependency as the gate lists themselves.
__global__ void gate_kernel(const float* __restrict__ x, const float* __restrict__ Wg,
                            const float* __restrict__ bg, int* __restrict__ counts,
                            int* __restrict__ tok_list, int* __restrict__ slot_list,
                            float* __restrict__ wslot, unsigned short* __restrict__ xb,
                            const float* __restrict__ W1, unsigned short* __restrict__ w1t) {
    __shared__ float tg[64][65];
    int wv = threadIdx.x >> 6, lane = threadIdx.x & 63;
    int n = blockIdx.x * 4 + wv;
    float acc[NE];
    #pragma unroll
    for (int e = 0; e < NE; e++) acc[e] = 0.f;
    const float* xr = x + (size_t)n * DIN;
    unsigned short* xbr = xb + (size_t)n * DIN;
    #pragma unroll
    for (int i = 0; i < DIN / 256; i++) {
        int d = i * 256 + lane * 4;
        float4 xv = *(const float4*)(xr + d);
        ushort4 o;
        o.x = f2bfu(xv.x); o.y = f2bfu(xv.y); o.z = f2bfu(xv.z); o.w = f2bfu(xv.w);
        *(ushort4*)(xbr + d) = o;
        const float* w = Wg + (size_t)d * NE;
        #pragma unroll
        for (int u = 0; u < 4; u++) {
            float xs = (&xv.x)[u];
            float4 w0 = *(const float4*)(w + u * NE);
            float4 w1 = *(const float4*)(w + u * NE + 4);
            acc[0] += xs * w0.x; acc[1] += xs * w0.y; acc[2] += xs * w0.z; acc[3] += xs * w0.w;
            acc[4] += xs * w1.x; acc[5] += xs * w1.y; acc[6] += xs * w1.z; acc[7] += xs * w1.w;
        }
    }
    #pragma unroll
    for (int off = 32; off; off >>= 1)
        #pragma unroll
        for (int e = 0; e < NE; e++) acc[e] += __shfl_down(acc[e], off);
    if (lane == 0) {
        float s[NE], p[NE];
        float mx = -1e30f;
        #pragma unroll
        for (int e = 0; e < NE; e++) { s[e] = acc[e] + bg[e]; mx = fmaxf(mx, s[e]); }
        float sum = 0.f;
        #pragma unroll
        for (int e = 0; e < NE; e++) { p[e] = expf(s[e] - mx); sum += p[e]; }
        float inv = 1.f / sum;
        int e0 = 0;
        #pragma unroll
        for (int e = 1; e < NE; e++) if (s[e] > s[e0]) e0 = e;
        int e1 = (e0 == 0) ? 1 : 0;
        #pragma unroll
        for (int e = 0; e < NE; e++) if (e != e0 && s[e] > s[e1]) e1 = e;
        float p0 = p[e0] * inv, p1 = p[e1] * inv;
        float rn = 1.f / (p0 + p1 + 1e-8f);
        int pos0 = atomicAdd(&counts[e0], 1);
        tok_list[e0 * N_TOK + pos0] = n; slot_list[e0 * N_TOK + pos0] = 2 * n;     wslot[e0 * N_TOK + pos0] = p0 * rn;
        int pos1 = atomicAdd(&counts[e1], 1);
        tok_list[e1 * N_TOK + pos1] = n; slot_list[e1 * N_TOK + pos1] = 2 * n + 1; wslot[e1 * N_TOK + pos1] = p1 * rn;
    }
    // fused W1 transpose: tiles laid out as grid (DHID/64=64, DIN/64=16, NE)
    #pragma unroll 1
    for (int j = 0; j < 4; j++) {
        int id = blockIdx.x * 4 + j;
        int bx = id & 63, by = (id >> 6) & 15, bz = id >> 10;
        transpose_tile(W1, w1t, DIN, DHID, bx, by, bz, tg);
    }
}

// ---------------- persistent grouped gather-GEMM, 128x128 tile, BK=64, bf16 MFMA ----------------
// R0 proven structure: grid = 1024 = 8 experts x 128 persistent blocks, expert e = blockIdx&7
// (XCD-pinned). SPLITK merged via f32 atomicAdd epilogue. XOR-swizzled LDS staging, 0 conflicts.
// GEMM1 additionally transposes W2 (8 tiles/block, interleaved after the block's first item):
// w2t is consumed only by GEMM2 (next launch), so no intra-kernel ordering is needed, and the
// streaming traffic hides under other blocks' MFMA phases. LDS staging tile overlays As/Bs pool.
template <int KDIM, int NDIM, bool IS_GEMM1, int SPLITK>
__global__ __launch_bounds__(256, 4)
void moe_gemm(const unsigned short* __restrict__ Asrc, const unsigned short* __restrict__ Bt,
              const float* __restrict__ bias, unsigned short* __restrict__ Hdst,
              float* __restrict__ Odst, const int* __restrict__ counts,
              const int* __restrict__ tok_list, const int* __restrict__ slot_list,
              const float* __restrict__ wslot,
              const float* __restrict__ W2src, unsigned short* __restrict__ w2t_dst) {
    constexpr int NT_N = NDIM / 128;
    constexpr int NT_M = N_TOK / 128;
    constexpr int KLEN = KDIM / SPLITK;

    int e = blockIdx.x & 7;
    int local = blockIdx.x >> 3;          // 0..127
    int count = counts[e];

    __shared__ __align__(16) unsigned short pool[2 * 128 * 64];  // As | Bs (32 KB)
    unsigned short* As = pool;
    unsigned short* Bs = pool + 128 * 64;
    __shared__ int rowid_s[128];
    __shared__ int outid_s[128];
    __shared__ float w_s[128];

    int tid = threadIdx.x;
    int lane = tid & 63;
    int wv = tid >> 6;
    int ric = lane >> 3;
    int k8  = (lane & 7) ^ ric;
    int wm = (wv >> 1) * 64, wn = (wv & 1) * 64;
    int r16 = lane & 15, quad = lane >> 4;

    bool tdone = !IS_GEMM1;

    for (int w = local; ; w += 128) {
        int tile_n = w % NT_N;
        int r = w / NT_N;
        int kh = r % SPLITK;
        int tile_m = r / SPLITK;
        if (tile_m >= NT_M) break;
        if (tile_m * 128 >= count) break;   // tile_m monotone => nothing left

        __syncthreads();   // prior item's epilogue reads of outid_s/w_s must finish
        if (tid < 128) {
            int rr = tile_m * 128 + tid;
            if (rr >= count) rr = tile_m * 128;
            int base = e * N_TOK + rr;
            if (IS_GEMM1) { rowid_s[tid] = tok_list[base]; outid_s[tid] = slot_list[base]; }
            else          { rowid_s[tid] = slot_list[base]; outid_s[tid] = tok_list[base]; w_s[tid] = wslot[base]; }
        }
        __syncthreads();

        const int k0 = kh * KLEN;
        const unsigned short* aptr[4];
        const unsigned short* bptr[4];
        #pragma unroll
        for (int i = 0; i < 4; i++) {
            int c = wv * 4 + i;
            int row = c * 8 + ric;
            aptr[i] = Asrc + (size_t)rowid_s[row] * KDIM + k0 + k8 * 8;
            bptr[i] = Bt + ((size_t)e * NDIM + tile_n * 128 + row) * KDIM + k0 + k8 * 8;
        }

        f32x4 acc[4][4];
        #pragma unroll
        for (int i = 0; i < 4; i++)
            #pragma unroll
            for (int j = 0; j < 4; j++) acc[i][j] = (f32x4){0.f, 0.f, 0.f, 0.f};

        for (int kk = 0; kk < KLEN / 64; kk++) {
            #pragma unroll
            for (int i = 0; i < 4; i++) {
                gload_lds16(aptr[i] + kk * 64, (void*)(As + (wv * 4 + i) * 512));
                gload_lds16(bptr[i] + kk * 64, (void*)(Bs + (wv * 4 + i) * 512));
            }
            __syncthreads();
            #pragma unroll
            for (int kh2 = 0; kh2 < 2; kh2++) {
                int swk = ((kh2 * 4 + quad) ^ (r16 & 7)) * 8;   // un-swizzle at read time
                bf16x8 av[4], bv[4];
                #pragma unroll
                for (int i = 0; i < 4; i++)
                    av[i] = *(const bf16x8*)(As + (wm + i * 16 + r16) * 64 + swk);
                #pragma unroll
                for (int j = 0; j < 4; j++)
                    bv[j] = *(const bf16x8*)(Bs + (wn + j * 16 + r16) * 64 + swk);
                #pragma unroll
                for (int i = 0; i < 4; i++)
                    #pragma unroll
                    for (int j = 0; j < 4; j++)
                        acc[i][j] = __builtin_amdgcn_mfma_f32_16x16x32_bf16(av[i], bv[j], acc[i][j], 0, 0, 0);
            }
            __syncthreads();
        }

        // epilogue: D row = quad*4+reg, col = lane&15 within each 16x16 tile
        float bias_r[4];
        #pragma unroll
        for (int j = 0; j < 4; j++)
            bias_r[j] = bias[(size_t)e * NDIM + tile_n * 128 + wn + j * 16 + r16];
        #pragma unroll
        for (int i = 0; i < 4; i++) {
            #pragma unroll
            for (int reg = 0; reg < 4; reg++) {
                int rr = wm + i * 16 + quad * 4 + reg;
                if (tile_m * 128 + rr >= count) continue;
                #pragma unroll
                for (int j = 0; j < 4; j++) {
                    int col = tile_n * 128 + wn + j * 16 + r16;
                    float v = acc[i][j][reg];
                    if (IS_GEMM1) {
                        v = fmaxf(v + bias_r[j], 0.f);
                        Hdst[(size_t)outid_s[rr] * NDIM + col] = f2bfu(v);
                    } else {
                        if (kh == 0) v += bias_r[j];
                        atomicAdd(&Odst[(size_t)outid_s[rr] * NDIM + col], w_s[rr] * v);
                    }
                }
            }
        }

        // fused W2 transpose after the first item (overlaps other blocks' compute)
        if constexpr (IS_GEMM1) {
            if (!tdone) {
                tdone = true;
                float (*t)[65] = (float(*)[65])pool;   // 16.7 KB <= 32 KB pool, As/Bs dead here
                #pragma unroll 1
                for (int j = 0; j < 8; j++) {
                    int id = blockIdx.x * 8 + j;       // tiles: grid (DOUT/64=16, DHID/64=64, NE)
                    int bx = id & 15, by = (id >> 4) & 63, bz = id >> 10;
                    transpose_tile(W2src, w2t_dst, DHID, DOUT, bx, by, bz, t);
                }
            }
        }
    }

    // blocks that ran out of items early still owe their transpose chunk
    if constexpr (IS_GEMM1) {
        if (!tdone) {
            float (*t)[65] = (float(*)[65])pool;
            #pragma unroll 1
            for (int j = 0; j < 8; j++) {
                int id = blockIdx.x * 8 + j;
                int bx = id & 15, by = (id >> 4) & 63, bz = id >> 10;
                transpose_tile(W2src, w2t_dst, DHID, DOUT, bx, by, bz, t);
            }
        }
    }
}

extern "C" void kernel_launch(void* const* d_in, const int* in_sizes, int n_in,
                              void* d_out, int out_size, void* d_ws, size_t ws_size,
                              hipStream_t stream) {
    const float* x  = (const float*)d_in[0];
    const float* W1 = (const float*)d_in[1];
    const float* b1 = (const float*)d_in[2];
    const float* W2 = (const float*)d_in[3];
    const float* b2 = (const float*)d_in[4];
    const float* Wg = (const float*)d_in[5];
    const float* bg = (const float*)d_in[6];
    float* out = (float*)d_out;

    char* ws = (char*)d_ws;
    unsigned short* xb  = (unsigned short*)(ws + 0);            // 16 MB
    unsigned short* w1t = (unsigned short*)(ws + 16777216);     // 64 MB  [E][DHID][DIN]
    unsigned short* w2t = (unsigned short*)(ws + 83886080);     // 64 MB  [E][DOUT][DHID]
    unsigned short* h   = (unsigned short*)(ws + 150994944);    // 128 MB [2N][DHID]
    int*   counts    = (int*)(ws + 285212672);
    int*   tok_list  = (int*)(ws + 285212928);
    int*   slot_list = (int*)(ws + 285475072);
    float* wslot     = (float*)(ws + 285737216);

    hipMemsetAsync(counts, 0, 256, stream);
    hipMemsetAsync(d_out, 0, (size_t)out_size * sizeof(float), stream);

    gate_kernel<<<N_TOK / 4, 256, 0, stream>>>(x, Wg, bg, counts, tok_list, slot_list, wslot, xb,
                                               W1, w1t);

    moe_gemm<DIN, DHID, true, 1><<<1024, 256, 0, stream>>>(
        xb, w1t, b1, h, nullptr, counts, tok_list, slot_list, wslot, W2, w2t);
    moe_gemm<DHID, DOUT, false, 2><<<1024, 256, 0, stream>>>(
        h, w2t, b2, nullptr, out, counts, tok_list, slot_list, wslot, nullptr, nullptr);
}